// Round 12
// baseline (84.776 us; speedup 1.0000x reference)
//
#include <hip/hip_runtime.h>

#define HH 256
#define WW 512
#define BQ 2
#define HWQ (HH*WW)
#define TW 68             // LDS tile cols (64 + 4 halo)
#define TH 12             // LDS tile rows (8 out + 4 halo)
#define CSTR 64           // LDS cell stride bytes (dense) + slot swizzle
#define TRL 20            // transpose stride (dwords)

#define RGASC 287.0f
#define CPC   1004.0f

typedef float f32x4 __attribute__((ext_vector_type(4)));
typedef short s16x8 __attribute__((ext_vector_type(8)));

// ---------------- static device scratch -------------------------------------
static __device__ uint4 g_Wm[25*64];          // packed A-fragments [tap][lane]
static __device__ float g_FC[HH*16];          // f_cor conv row-term [r][o]
static __device__ float g_S [HH*3*16];        // mean-correction  [r][k][o]
static __device__ float g_part[2][6*512];     // per-block partial sums (parity dbuf)
static __device__ uint4 g_st0[2][BQ*HWQ];     // bf16 state: T0 q0 u0 v0 T1 q1 u1 v1
static __device__ uint2 g_st1[2][BQ*HWQ];     // bf16 state: T2 q2 u2 v2
static __device__ float g_aT [BQ*3*HWQ];      // RK4 accumulators (f32)
static __device__ float g_aq [BQ*3*HWQ];
static __device__ float g_auv[BQ*3*HWQ*2];

// Cell slot map (32 bf16): s0-11: [T0,q0,u0,v0, T1,q1,u1,v1, T2,q2,u2,v2]
// s12-14: KE0-2, s15: 0, s16-21: zT (T_k*u_k, T_k*v_k), s22-27: zq, s28-31: 0.
// Packed state words w0..w5 == cell words pk[0..5] verbatim (direct copy);
// staging computes only the derived KE/z channels.
// LDS slot swizzle: chunk g of cell at tile-col lc stored at slot (g+key(lc))&3,
// key(lc) = (lc + (lc>>2)) & 3 (nt-invariant: lc->lc+16 adds 20 ≡ 0 mod 4).
// Parity: prelude writes buf1; stage s reads buf (s&1)^1, writes buf s&1.
// Output rows o: 0-2 DIV_k, 3-5 TK_k, 6-8 QK_k, 9-14 (U0,V0,U1,V1,U2,V2), 15 pad.

__device__ __forceinline__ unsigned short f2bf(float f) {   // RNE f32->bf16
  unsigned int u = __builtin_bit_cast(unsigned int, f);
  u += 0x7fffu + ((u >> 16) & 1u);
  return (unsigned short)(u >> 16);
}
__device__ __forceinline__ float bflo(unsigned int d) {
  return __builtin_bit_cast(float, d << 16);
}
__device__ __forceinline__ float bfhi(unsigned int d) {
  return __builtin_bit_cast(float, d & 0xffff0000u);
}
__device__ __forceinline__ int foMap(int o) {   // full scalar-output channel
  return (o < 3) ? 6*o + 3 : (o < 6) ? 6*(o-3) + 4 : 6*(o-6) + 5;
}

// ---------------- prelude: T0 means + input state pack + weight pack ---------
__global__ __launch_bounds__(256) void prelude_kernel(
    const float* __restrict__ uv0, const float* __restrict__ T0,
    const float* __restrict__ q0,
    const float* __restrict__ k_ss, const float* __restrict__ k_vs,
    const float* __restrict__ k_sv, const float* __restrict__ k_vv,
    const float* __restrict__ k_vs2, const float* __restrict__ f_cor)
{
  if (blockIdx.x < 768) {                 // meanpart: 1024 elements per block
    int bk = blockIdx.x >> 7, chunk = blockIdx.x & 127;
    const float* p = T0 + bk*HWQ + chunk*1024;
    float v = p[threadIdx.x] + p[threadIdx.x+256]
            + p[threadIdx.x+512] + p[threadIdx.x+768];
    int l = threadIdx.x & 63, w = threadIdx.x >> 6;
    #pragma unroll
    for (int off=32; off; off >>= 1) v += __shfl_down(v, off);
    __shared__ float sr[4];
    if (l == 0) sr[w] = v;
    __syncthreads();
    if (threadIdx.x == 0) g_part[0][bk*512 + chunk] = sr[0]+sr[1]+sr[2]+sr[3];
    return;
  }
  if (blockIdx.x < 768 + 1024) {          // pack input state -> parity buf 1
    int idx = (blockIdx.x - 768)*256 + threadIdx.x;   // linear b*HWQ + rc
    int b  = idx >> 17;                   // HWQ = 2^17
    int rc = idx & (HWQ-1);
    unsigned int wd[6];
    #pragma unroll
    for (int k=0;k<3;++k) {
      int pix = (b*3+k)*HWQ + rc;
      float2 uvv = *(const float2*)(uv0 + 2*pix);
      wd[2*k]   = f2bf(T0[pix]) | ((unsigned)f2bf(q0[pix]) << 16);
      wd[2*k+1] = f2bf(uvv.x)   | ((unsigned)f2bf(uvv.y)   << 16);
    }
    g_st0[1][idx] = make_uint4(wd[0], wd[1], wd[2], wd[3]);
    g_st1[1][idx] = make_uint2(wd[4], wd[5]);
    return;
  }
  int tid = (blockIdx.x - 768 - 1024)*256 + threadIdx.x;
  if (tid < 1600) {                       // A-fragments g_Wm[t][lane]
    int l = tid & 63, t = tid >> 6;
    int o = l & 15, g = l >> 4;
    int dy = t/5, dx = t%5;
    unsigned short h[8];
    #pragma unroll
    for (int e=0;e<8;++e) {
      int s = 8*g + e; float val = 0.f;
      if (o < 15) {
        int fo = foMap(o), vo = o - 9;
        if (s < 12) {
          int k = s >> 2, c4 = s & 3;
          if (c4 >= 2) {                  // u_k / v_k
            int j = 2*k + (c4-2);
            val = (o<9) ? k_vs[((fo*6+j)*5+dy)*5+dx]
                        : k_vv[((vo*6+j)*5+dy)*5+dx];
          } else {                        // T_k (+fold T_anom) / q_k
            int ifull = 6*k + ((c4==0) ? 4 : 5);
            val = (o<9) ? k_ss[((fo*19+ifull)*5+dy)*5+dx]
                        : k_sv[((vo*19+ifull)*5+dy)*5+dx];
            if (c4 == 0) {
              int ia = 6*k;               // T_anom channel folded into T
              val += (o<9) ? k_ss[((fo*19+ia)*5+dy)*5+dx]
                           : k_sv[((vo*19+ia)*5+dy)*5+dx];
            }
          }
        } else if (s < 15) {              // KE_k
          int ifull = 6*(s-12) + 1;
          val = (o<9) ? k_ss[((fo*19+ifull)*5+dy)*5+dx]
                      : k_sv[((vo*19+ifull)*5+dy)*5+dx];
        } else if (s >= 16 && s < 22) {   // zT_{k,c} -> only output TK_k
          int k = (s-16)>>1, c = (s-16)&1;
          if (o == 3+k) val = k_vs2[(((6*k+4)*6 + 2*k+c)*5+dy)*5+dx];
        } else if (s >= 22 && s < 28) {   // zq_{k,c} -> only output QK_k
          int k = (s-22)>>1, c = (s-22)&1;
          if (o == 6+k) val = k_vs2[(((6*k+5)*6 + 2*k+c)*5+dy)*5+dx];
        }
      }
      h[e] = f2bf(val);
    }
    uint4 wv;
    wv.x = h[0] | ((unsigned)h[1]<<16);  wv.y = h[2] | ((unsigned)h[3]<<16);
    wv.z = h[4] | ((unsigned)h[5]<<16);  wv.w = h[6] | ((unsigned)h[7]<<16);
    g_Wm[tid] = wv;
  } else if (tid < 1600 + HH*16) {        // g_FC[r][o]: f_cor channel conv term
    int e = tid - 1600;
    int o = e & 15, r = e >> 4;
    float val = 0.f;
    if (o < 15) {
      int fo = foMap(o), vo = o - 9;
      for (int t=0;t<25;++t) {
        int dy = t/5, dx = t%5;
        int ar = r + dy - 2;
        if (ar < 0 || ar >= HH) continue;
        float f = f_cor[ar];
        float wv = (o<9) ? k_ss[((fo*19+18)*5+dy)*5+dx]
                         : k_sv[((vo*19+18)*5+dy)*5+dx];
        val += wv * f;
      }
    }
    g_FC[e] = val;
  } else if (tid < 1600 + HH*16 + HH*3*16) {  // g_S[r][k][o] mean-correction
    int e = tid - 1600 - HH*16;
    int o = e & 15; int rk = e >> 4;
    int k = rk % 3, r = rk / 3;
    float val = 0.f;
    if (o < 15) {
      int fo = foMap(o), vo = o - 9;
      int ia = 6*k;                       // T_anom weight sum over valid taps
      for (int t=0;t<25;++t) {
        int dy = t/5, dx = t%5;
        int ar = r + dy - 2;
        if (ar < 0 || ar >= HH) continue;
        val += (o<9) ? k_ss[((fo*19+ia)*5+dy)*5+dx]
                     : k_sv[((vo*19+ia)*5+dy)*5+dx];
      }
    }
    g_S[e] = val;
  }
}

// ---------------- fused stage: mean + build field + MFMA conv + RK4 ----------
__global__ __launch_bounds__(512, 4) void conv_kernel(
    const float* __restrict__ ke_w,
    const float* __restrict__ f_cor, const float* __restrict__ p_lev,
    const float* __restrict__ delta_p,
    const float* __restrict__ uv0, const float* __restrict__ T0,
    const float* __restrict__ q0,
    float* __restrict__ out, const int* __restrict__ dtp, int stage)
{
  __shared__ __align__(16) char s_raw[TH*TW*CSTR];   // 52224 B; reused for transpose
  __shared__ float s_red[8][3];
  __shared__ float s_mean[3];

  const int tid = threadIdx.x;
  const int w   = tid >> 6;                     // wave 0..7 -> output row
  const int l   = tid & 63;
  const int b   = blockIdx.z;
  const int c0  = blockIdx.x << 6;
  const int R0  = blockIdx.y << 3;
  const int r   = R0 + w;

  // ---- inline mean: waves 0-2 reduce this stage's partials ------------------
  if (w < 3) {
    const float* gp = g_part[stage & 1] + (b*3 + w)*512;
    float s;
    if (stage == 0) {
      s = gp[l] + gp[l+64];                     // 128 prelude partials
    } else {
      s = gp[l] + gp[l+64] + gp[l+128] + gp[l+192];   // 256 conv partials
    }
    #pragma unroll
    for (int off=32; off; off >>= 1) s += __shfl_down(s, off);
    if (l == 0) s_mean[w] = s * (1.0f/(float)HWQ);
  }

  // ---- staging: packed state -> bf16 cells (words 0-5 verbatim) -------------
  const int rb = (stage & 1) ^ 1;               // read parity (prelude -> buf1)
  const float kw00=ke_w[0], kw01=ke_w[1], kw02=ke_w[2];
  const float kw10=ke_w[3], kw11=ke_w[4], kw12=ke_w[5];
  const float kw20=ke_w[6], kw21=ke_w[7], kw22=ke_w[8];
  for (int e = tid; e < TH*TW; e += 512) {
    int lr = e / TW, lc = e - lr*TW;
    int row = R0 + lr - 2;
    int col = (c0 + lc - 2) & (WW-1);
    unsigned int pk[16];
    #pragma unroll
    for (int i=0;i<16;++i) pk[i] = 0;
    if (row >= 0 && row < HH) {
      const int idx = b*HWQ + row*WW + col;
      const uint4 a  = g_st0[rb][idx];
      const uint2 bv = g_st1[rb][idx];
      pk[0]=a.x; pk[1]=a.y; pk[2]=a.z; pk[3]=a.w; pk[4]=bv.x; pk[5]=bv.y;
      float T[3], q[3], u[3], v[3];
      T[0]=bflo(a.x);  q[0]=bfhi(a.x);  u[0]=bflo(a.y);  v[0]=bfhi(a.y);
      T[1]=bflo(a.z);  q[1]=bfhi(a.z);  u[1]=bflo(a.w);  v[1]=bfhi(a.w);
      T[2]=bflo(bv.x); q[2]=bfhi(bv.x); u[2]=bflo(bv.y); v[2]=bfhi(bv.y);
      float u2[3];
      #pragma unroll
      for (int k=0;k<3;++k) u2[k] = u[k]*u[k] + v[k]*v[k];
      float ke0 = kw00*u2[0] + kw01*u2[1] + kw02*u2[2];
      float ke1 = kw10*u2[0] + kw11*u2[1] + kw12*u2[2];
      float ke2 = kw20*u2[0] + kw21*u2[1] + kw22*u2[2];
      pk[6] = f2bf(ke0) | ((unsigned)f2bf(ke1) << 16);   // s12,s13
      pk[7] = f2bf(ke2);                                 // s14 (s15 = 0)
      #pragma unroll
      for (int k=0;k<3;++k) {
        pk[8+k]  = f2bf(T[k]*u[k]) | ((unsigned)f2bf(T[k]*v[k]) << 16); // zT
        pk[11+k] = f2bf(q[k]*u[k]) | ((unsigned)f2bf(q[k]*v[k]) << 16); // zq
      }
    }
    const int key = (lc + (lc >> 2)) & 3;       // slot swizzle (write side)
    uint4* cell = (uint4*)(s_raw + e*CSTR);
    cell[(0+key)&3] = make_uint4(pk[0],pk[1],pk[2],pk[3]);
    cell[(1+key)&3] = make_uint4(pk[4],pk[5],pk[6],pk[7]);
    cell[(2+key)&3] = make_uint4(pk[8],pk[9],pk[10],pk[11]);
    cell[(3+key)&3] = make_uint4(pk[12],pk[13],pk[14],pk[15]);
  }
  __syncthreads();

  // ---- acc init: f_cor row term + mean correction ---------------------------
  const int gi = l >> 4;
  const int m  = l & 15;
  f32x4 acc[4];
  {
    float4 fc = *(const float4*)(g_FC + r*16 + gi*4);
    f32x4 base = (f32x4){fc.x, fc.y, fc.z, fc.w};
    #pragma unroll
    for (int k=0;k<3;++k) {
      float mk = s_mean[k];
      float4 sk = *(const float4*)(g_S + (r*3+k)*16 + gi*4);
      base.x -= mk*sk.x; base.y -= mk*sk.y; base.z -= mk*sk.z; base.w -= mk*sk.w;
    }
    #pragma unroll
    for (int nt=0;nt<4;++nt) acc[nt] = base;
  }

  // ---- 25-tap MFMA loop: swizzled conflict-free B reads ----------------------
  const char* sb = s_raw;
  #pragma unroll 5
  for (int t=0;t<25;++t) {
    const int dy = t/5, dx = t%5;
    const uint4 aw = g_Wm[t*64 + l];
    const s16x8 af = __builtin_bit_cast(s16x8, aw);
    const int lc0  = dx + m;
    const int slot = (gi + lc0 + (lc0 >> 2)) & 3;   // nt-invariant key
    const int base = (((w+dy)*TW) + lc0)*CSTR + slot*16;
    #pragma unroll
    for (int nt=0;nt<4;++nt) {
      const s16x8 bf = __builtin_bit_cast(s16x8,
          *(const uint4*)(sb + base + nt*(16*CSTR)));
      acc[nt] = __builtin_amdgcn_mfma_f32_16x16x32_bf16(af, bf, acc[nt], 0, 0, 0);
    }
  }

  // center values (bf16) for thermo + Coriolis (chunks 0,1 at swizzled slots)
  float Tc[3], ucv[3], vcv[3];
  {
    const int lcc = l + 2;
    const int keyc = (lcc + (lcc >> 2)) & 3;
    const char* cc = sb + (((w+2)*TW) + lcc)*CSTR;
    const uint4 c0v = *(const uint4*)(cc + ((0+keyc)&3)*16);  // s0-7
    const uint2 c1v = *(const uint2*)(cc + ((1+keyc)&3)*16);  // s8-11
    Tc[0]=bflo(c0v.x); ucv[0]=bflo(c0v.y); vcv[0]=bfhi(c0v.y);
    Tc[1]=bflo(c0v.z); ucv[1]=bflo(c0v.w); vcv[1]=bfhi(c0v.w);
    Tc[2]=bflo(c1v.x); ucv[2]=bflo(c1v.y); vcv[2]=bfhi(c1v.y);
  }
  __syncthreads();                              // tile dead; reuse for transpose

  // transpose D fragments -> per-lane all 16 outputs (per-wave region)
  float* sf = (float*)s_raw;
  const int trb = w * (64*TRL);
  #pragma unroll
  for (int nt=0;nt<4;++nt)
    *(f32x4*)(sf + trb + (nt*16 + m)*TRL + gi*4) = acc[nt];
  float y[16];
  #pragma unroll
  for (int q=0;q<4;++q) {
    float4 v = *(const float4*)(sf + trb + l*TRL + q*4);
    y[4*q+0]=v.x; y[4*q+1]=v.y; y[4*q+2]=v.z; y[4*q+3]=v.w;
  }

  // ----------------- physics + RK4 ------------------------------------------
  const int c = c0 + l;
  const float fcv = f_cor[r];
  const float dtf = (float)(*dtp);
  const float an  = (stage==2) ? dtf : 0.5f*dtf;
  const float c6  = dtf/6.0f;
  const float p0=p_lev[0], p1=p_lev[1], p2=p_lev[2];
  const float dp0=delta_p[0], dp1=delta_p[1], dp2=delta_p[2];
  const float r10 = 1.0f/(p1-p0), r20 = 1.0f/(p2-p0), r21 = 1.0f/(p2-p1);
  const float roc = RGASC/CPC;
  const float rp0 = 1.0f/p0, rp1 = 1.0f/p1, rp2 = 1.0f/p2;
  const int OUT_T = BQ*3*HWQ*2;
  const int OUT_Q = OUT_T + BQ*3*HWQ;

  float kT[3], kq[3], ku[3], kv[3];
  #pragma unroll
  for (int k=0;k<3;++k) {
    kT[k] = y[3+k];
    kq[k] = y[6+k];
    ku[k] = y[9+2*k]  + fcv*vcv[k];             // Coriolis (svp collapses to this)
    kv[k] = y[10+2*k] - fcv*ucv[k];
  }
  const float oh1 = y[0]*dp0;
  const float oh2 = oh1 + y[1]*dp1;
  const float oh3 = oh2 + y[2]*dp2;
  const float om0 = 0.5f*oh1, om1 = 0.5f*(oh1+oh2), om2 = 0.5f*(oh2+oh3);
  kT[0] += om0*(roc*Tc[0]*rp0 - (Tc[1]-Tc[0])*r10);
  kT[1] += om1*(roc*Tc[1]*rp1 - (Tc[2]-Tc[0])*r20);
  kT[2] += om2*(roc*Tc[2]*rp2 - (Tc[2]-Tc[1])*r21);

  if (stage < 3) {
    float Tn[3], qn[3], un[3], vn[3];
    #pragma unroll
    for (int k=0;k<3;++k) {
      const int pT = ((b*3+k)*HH + r)*WW + c;
      const int pU = pT*2;
      if (stage == 0) {
        g_aT[pT] = kT[k];  g_aq[pT] = kq[k];
        g_auv[pU] = ku[k]; g_auv[pU+1] = kv[k];
      } else {
        g_aT[pT] += 2.0f*kT[k];  g_aq[pT] += 2.0f*kq[k];
        g_auv[pU] += 2.0f*ku[k]; g_auv[pU+1] += 2.0f*kv[k];
      }
      Tn[k] = T0[pT] + an*kT[k];
      qn[k] = q0[pT] + an*kq[k];
      un[k] = uv0[pU]   + an*ku[k];
      vn[k] = uv0[pU+1] + an*kv[k];
    }
    // packed bf16 state -> parity buffer (stage s writes buf s&1)
    const int sidx = b*HWQ + r*WW + c;
    unsigned int w0 = f2bf(Tn[0]) | ((unsigned)f2bf(qn[0])<<16);
    unsigned int w1 = f2bf(un[0]) | ((unsigned)f2bf(vn[0])<<16);
    unsigned int w2 = f2bf(Tn[1]) | ((unsigned)f2bf(qn[1])<<16);
    unsigned int w3 = f2bf(un[1]) | ((unsigned)f2bf(vn[1])<<16);
    unsigned int w4 = f2bf(Tn[2]) | ((unsigned)f2bf(qn[2])<<16);
    unsigned int w5 = f2bf(un[2]) | ((unsigned)f2bf(vn[2])<<16);
    g_st0[stage & 1][sidx] = make_uint4(w0, w1, w2, w3);
    g_st1[stage & 1][sidx] = make_uint2(w4, w5);

    // partial sums of next-stage T for its mean (opposite parity buffer)
    #pragma unroll
    for (int k=0;k<3;++k) {
      float v = Tn[k];
      #pragma unroll
      for (int off=32; off; off >>= 1) v += __shfl_down(v, off);
      if (l == 0) s_red[w][k] = v;
    }
    __syncthreads();
    if (tid == 0) {
      #pragma unroll
      for (int k=0;k<3;++k) {
        float s = 0.f;
        #pragma unroll
        for (int ww=0;ww<8;++ww) s += s_red[ww][k];
        g_part[(stage & 1) ^ 1][(b*3+k)*512 + blockIdx.y*8 + blockIdx.x] = s;
      }
    }
  } else {
    #pragma unroll
    for (int k=0;k<3;++k) {
      const int pT = ((b*3+k)*HH + r)*WW + c;
      const int pU = pT*2;
      out[pU]         = uv0[pU]   + c6*(g_auv[pU]   + ku[k]);
      out[pU+1]       = uv0[pU+1] + c6*(g_auv[pU+1] + kv[k]);
      out[OUT_T + pT] = T0[pT]    + c6*(g_aT[pT] + kT[k]);
      out[OUT_Q + pT] = q0[pT]    + c6*(g_aq[pT] + kq[k]);
    }
  }
}

// -----------------------------------------------------------------------------
extern "C" void kernel_launch(void* const* d_in, const int* in_sizes, int n_in,
                              void* d_out, int out_size, void* d_ws, size_t ws_size,
                              hipStream_t stream) {
  (void)in_sizes; (void)n_in; (void)d_ws; (void)ws_size; (void)out_size;
  const float* uv0   = (const float*)d_in[0];
  const float* T0    = (const float*)d_in[1];
  const float* q0    = (const float*)d_in[2];
  const float* k_ss  = (const float*)d_in[3];
  const float* k_vs  = (const float*)d_in[4];
  const float* k_sv  = (const float*)d_in[5];
  const float* k_vv  = (const float*)d_in[6];
  const float* k_vs2 = (const float*)d_in[7];
  const float* ke_w  = (const float*)d_in[10];
  const float* f_cor = (const float*)d_in[11];
  const float* p_lev = (const float*)d_in[12];
  const float* dpv   = (const float*)d_in[13];
  const int*   dtp   = (const int*)d_in[14];
  float* out = (float*)d_out;

  // prelude: 768 mean + 1024 state-pack + 71 weight-pack blocks
  prelude_kernel<<<1863, 256, 0, stream>>>(uv0, T0, q0,
                                           k_ss, k_vs, k_sv, k_vv, k_vs2, f_cor);

  for (int st = 0; st < 4; ++st) {
    conv_kernel<<<dim3(8,32,2), 512, 0, stream>>>(
        ke_w, f_cor, p_lev, dpv, uv0, T0, q0, out, dtp, st);
  }
}

// Round 13
// 82.137 us; speedup vs baseline: 1.0321x; 1.0321x over previous
//
#include <hip/hip_runtime.h>

#define HH 256
#define WW 512
#define BQ 2
#define HWQ (HH*WW)
#define TW 68             // LDS tile cols (64 + 4 halo)
#define TH 12             // LDS tile rows (8 out + 4 halo)
#define CSTR 64           // LDS cell stride bytes (dense) + slot swizzle
#define TRL 20            // transpose stride (dwords)

#define RGASC 287.0f
#define CPC   1004.0f

typedef float f32x4 __attribute__((ext_vector_type(4)));
typedef short s16x8 __attribute__((ext_vector_type(8)));

// ---------------- static device scratch -------------------------------------
static __device__ uint4 g_Wm[25*64];          // packed A-fragments [tap][lane]
static __device__ float g_FC[HH*16];          // f_cor conv row-term [r][o]
static __device__ float g_S [HH*3*16];        // mean-correction  [r][k][o]
static __device__ float g_part[2][6*512];     // per-block partial sums (parity dbuf)
static __device__ uint4 g_st0[2][BQ*HWQ];     // bf16 state: T0 q0 u0 v0 T1 q1 u1 v1
static __device__ uint2 g_st1[2][BQ*HWQ];     // bf16 state: T2 q2 u2 v2
static __device__ float g_aT [BQ*3*HWQ];      // RK4 accumulators (f32)
static __device__ float g_aq [BQ*3*HWQ];
static __device__ float g_auv[BQ*3*HWQ*2];

// Cell slot map (32 bf16): s0-11: [T0,q0,u0,v0, T1,q1,u1,v1, T2,q2,u2,v2]
// s12-14: KE0-2, s15: 0, s16-21: zT (T_k*u_k, T_k*v_k), s22-27: zq, s28-31: 0.
// LDS slot swizzle: chunk g of cell at tile-col lc stored at slot (g+key(lc))&3,
// key(lc) = (lc + (lc>>2)) & 3 (nt-invariant: lc->lc+16 adds 20 ≡ 0 mod 4).
// Stage state (parity dbuf): stage s writes buf s&1, stage s+1 reads buf s&1.
// Output rows o: 0-2 DIV_k, 3-5 TK_k, 6-8 QK_k, 9-14 (U0,V0,U1,V1,U2,V2), 15 pad.

__device__ __forceinline__ unsigned short f2bf(float f) {   // RNE f32->bf16
  unsigned int u = __builtin_bit_cast(unsigned int, f);
  u += 0x7fffu + ((u >> 16) & 1u);
  return (unsigned short)(u >> 16);
}
__device__ __forceinline__ float bflo(unsigned int d) {
  return __builtin_bit_cast(float, d << 16);
}
__device__ __forceinline__ float bfhi(unsigned int d) {
  return __builtin_bit_cast(float, d & 0xffff0000u);
}
__device__ __forceinline__ int foMap(int o) {   // full scalar-output channel
  return (o < 3) ? 6*o + 3 : (o < 6) ? 6*(o-3) + 4 : 6*(o-6) + 5;
}

// ---------------- prelude: input-T partial means + weight packing ------------
__global__ __launch_bounds__(256) void prelude_kernel(
    const float* __restrict__ T0,
    const float* __restrict__ k_ss, const float* __restrict__ k_vs,
    const float* __restrict__ k_sv, const float* __restrict__ k_vv,
    const float* __restrict__ k_vs2, const float* __restrict__ f_cor)
{
  if (blockIdx.x < 768) {                 // meanpart: 1024 elements per block
    int bk = blockIdx.x >> 7, chunk = blockIdx.x & 127;
    const float* p = T0 + bk*HWQ + chunk*1024;
    float v = p[threadIdx.x] + p[threadIdx.x+256]
            + p[threadIdx.x+512] + p[threadIdx.x+768];
    int l = threadIdx.x & 63, w = threadIdx.x >> 6;
    #pragma unroll
    for (int off=32; off; off >>= 1) v += __shfl_down(v, off);
    __shared__ float sr[4];
    if (l == 0) sr[w] = v;
    __syncthreads();
    if (threadIdx.x == 0) g_part[0][bk*512 + chunk] = sr[0]+sr[1]+sr[2]+sr[3];
    return;
  }
  int tid = (blockIdx.x - 768)*256 + threadIdx.x;
  if (tid < 1600) {                       // A-fragments g_Wm[t][lane]
    int l = tid & 63, t = tid >> 6;
    int o = l & 15, g = l >> 4;
    int dy = t/5, dx = t%5;
    unsigned short h[8];
    #pragma unroll
    for (int e=0;e<8;++e) {
      int s = 8*g + e; float val = 0.f;
      if (o < 15) {
        int fo = foMap(o), vo = o - 9;
        if (s < 12) {
          int k = s >> 2, c4 = s & 3;
          if (c4 >= 2) {                  // u_k / v_k
            int j = 2*k + (c4-2);
            val = (o<9) ? k_vs[((fo*6+j)*5+dy)*5+dx]
                        : k_vv[((vo*6+j)*5+dy)*5+dx];
          } else {                        // T_k (+fold T_anom) / q_k
            int ifull = 6*k + ((c4==0) ? 4 : 5);
            val = (o<9) ? k_ss[((fo*19+ifull)*5+dy)*5+dx]
                        : k_sv[((vo*19+ifull)*5+dy)*5+dx];
            if (c4 == 0) {
              int ia = 6*k;               // T_anom channel folded into T
              val += (o<9) ? k_ss[((fo*19+ia)*5+dy)*5+dx]
                           : k_sv[((vo*19+ia)*5+dy)*5+dx];
            }
          }
        } else if (s < 15) {              // KE_k
          int ifull = 6*(s-12) + 1;
          val = (o<9) ? k_ss[((fo*19+ifull)*5+dy)*5+dx]
                      : k_sv[((vo*19+ifull)*5+dy)*5+dx];
        } else if (s >= 16 && s < 22) {   // zT_{k,c} -> only output TK_k
          int k = (s-16)>>1, c = (s-16)&1;
          if (o == 3+k) val = k_vs2[(((6*k+4)*6 + 2*k+c)*5+dy)*5+dx];
        } else if (s >= 22 && s < 28) {   // zq_{k,c} -> only output QK_k
          int k = (s-22)>>1, c = (s-22)&1;
          if (o == 6+k) val = k_vs2[(((6*k+5)*6 + 2*k+c)*5+dy)*5+dx];
        }
      }
      h[e] = f2bf(val);
    }
    uint4 wv;
    wv.x = h[0] | ((unsigned)h[1]<<16);  wv.y = h[2] | ((unsigned)h[3]<<16);
    wv.z = h[4] | ((unsigned)h[5]<<16);  wv.w = h[6] | ((unsigned)h[7]<<16);
    g_Wm[tid] = wv;
  } else if (tid < 1600 + HH*16) {        // g_FC[r][o]: f_cor channel conv term
    int e = tid - 1600;
    int o = e & 15, r = e >> 4;
    float val = 0.f;
    if (o < 15) {
      int fo = foMap(o), vo = o - 9;
      for (int t=0;t<25;++t) {
        int dy = t/5, dx = t%5;
        int ar = r + dy - 2;
        if (ar < 0 || ar >= HH) continue;
        float f = f_cor[ar];
        float wv = (o<9) ? k_ss[((fo*19+18)*5+dy)*5+dx]
                         : k_sv[((vo*19+18)*5+dy)*5+dx];
        val += wv * f;
      }
    }
    g_FC[e] = val;
  } else if (tid < 1600 + HH*16 + HH*3*16) {  // g_S[r][k][o] mean-correction
    int e = tid - 1600 - HH*16;
    int o = e & 15; int rk = e >> 4;
    int k = rk % 3, r = rk / 3;
    float val = 0.f;
    if (o < 15) {
      int fo = foMap(o), vo = o - 9;
      int ia = 6*k;                       // T_anom weight sum over valid taps
      for (int t=0;t<25;++t) {
        int dy = t/5, dx = t%5;
        int ar = r + dy - 2;
        if (ar < 0 || ar >= HH) continue;
        val += (o<9) ? k_ss[((fo*19+ia)*5+dy)*5+dx]
                     : k_sv[((vo*19+ia)*5+dy)*5+dx];
      }
    }
    g_S[e] = val;
  }
}

// ---------------- fused stage: mean + build field + MFMA conv + RK4 ----------
__global__ __launch_bounds__(512, 4) void conv_kernel(
    const float* __restrict__ ke_w,
    const float* __restrict__ f_cor, const float* __restrict__ p_lev,
    const float* __restrict__ delta_p,
    const float* __restrict__ uv0, const float* __restrict__ T0,
    const float* __restrict__ q0,
    float* __restrict__ out, const int* __restrict__ dtp, int stage)
{
  __shared__ __align__(16) char s_raw[TH*TW*CSTR];   // 52224 B; reused for transpose
  __shared__ float s_red[8][3];
  __shared__ float s_mean[3];

  const int tid = threadIdx.x;
  const int w   = tid >> 6;                     // wave 0..7 -> output row
  const int l   = tid & 63;
  const int b   = blockIdx.z;
  const int c0  = blockIdx.x << 6;
  const int R0  = blockIdx.y << 3;
  const int r   = R0 + w;

  // ---- inline mean: waves 0-2 reduce this stage's partials ------------------
  if (w < 3) {
    const float* gp = g_part[stage & 1] + (b*3 + w)*512;
    float s;
    if (stage == 0) {
      s = gp[l] + gp[l+64];                     // 128 prelude partials
    } else {
      s = gp[l] + gp[l+64] + gp[l+128] + gp[l+192];   // 256 conv partials
    }
    #pragma unroll
    for (int off=32; off; off >>= 1) s += __shfl_down(s, off);
    if (l == 0) s_mean[w] = s * (1.0f/(float)HWQ);
  }

  // ---- fused prep: state -> bf16 cells (halo rows zero) ----------------------
  const float kw00=ke_w[0], kw01=ke_w[1], kw02=ke_w[2];
  const float kw10=ke_w[3], kw11=ke_w[4], kw12=ke_w[5];
  const float kw20=ke_w[6], kw21=ke_w[7], kw22=ke_w[8];
  for (int e = tid; e < TH*TW; e += 512) {
    int lr = e / TW, lc = e - lr*TW;
    int row = R0 + lr - 2;
    int col = (c0 + lc - 2) & (WW-1);
    unsigned int pk[16];
    #pragma unroll
    for (int i=0;i<16;++i) pk[i] = 0;
    if (row >= 0 && row < HH) {
      float T[3], q[3], u[3], v[3];
      if (stage == 0) {
        #pragma unroll
        for (int k=0;k<3;++k) {
          int pix = ((b*3+k)*HH + row)*WW + col;
          T[k] = T0[pix]; q[k] = q0[pix];
          float2 uvv = *(const float2*)(uv0 + 2*pix);
          u[k] = uvv.x; v[k] = uvv.y;
        }
      } else {
        const int idx = (b*HH + row)*WW + col;
        const uint4 a  = g_st0[(stage-1)&1][idx];
        const uint2 bv = g_st1[(stage-1)&1][idx];
        T[0]=bflo(a.x);  q[0]=bfhi(a.x);  u[0]=bflo(a.y);  v[0]=bfhi(a.y);
        T[1]=bflo(a.z);  q[1]=bfhi(a.z);  u[1]=bflo(a.w);  v[1]=bfhi(a.w);
        T[2]=bflo(bv.x); q[2]=bfhi(bv.x); u[2]=bflo(bv.y); v[2]=bfhi(bv.y);
      }
      float u2[3];
      #pragma unroll
      for (int k=0;k<3;++k) u2[k] = u[k]*u[k] + v[k]*v[k];
      float ke0 = kw00*u2[0] + kw01*u2[1] + kw02*u2[2];
      float ke1 = kw10*u2[0] + kw11*u2[1] + kw12*u2[2];
      float ke2 = kw20*u2[0] + kw21*u2[1] + kw22*u2[2];
      unsigned short hs[28];
      #pragma unroll
      for (int k=0;k<3;++k) {
        hs[4*k+0] = f2bf(T[k]); hs[4*k+1] = f2bf(q[k]);
        hs[4*k+2] = f2bf(u[k]); hs[4*k+3] = f2bf(v[k]);
      }
      hs[12]=f2bf(ke0); hs[13]=f2bf(ke1); hs[14]=f2bf(ke2); hs[15]=0;
      #pragma unroll
      for (int k=0;k<3;++k) {
        hs[16+2*k] = f2bf(T[k]*u[k]); hs[17+2*k] = f2bf(T[k]*v[k]);
        hs[22+2*k] = f2bf(q[k]*u[k]); hs[23+2*k] = f2bf(q[k]*v[k]);
      }
      #pragma unroll
      for (int i=0;i<14;++i) pk[i] = hs[2*i] | ((unsigned)hs[2*i+1] << 16);
    }
    const int key = (lc + (lc >> 2)) & 3;       // slot swizzle (write side)
    uint4* cell = (uint4*)(s_raw + e*CSTR);
    cell[(0+key)&3] = make_uint4(pk[0],pk[1],pk[2],pk[3]);
    cell[(1+key)&3] = make_uint4(pk[4],pk[5],pk[6],pk[7]);
    cell[(2+key)&3] = make_uint4(pk[8],pk[9],pk[10],pk[11]);
    cell[(3+key)&3] = make_uint4(pk[12],pk[13],pk[14],pk[15]);
  }
  __syncthreads();

  // ---- acc init: f_cor row term + mean correction ---------------------------
  const int gi = l >> 4;
  const int m  = l & 15;
  f32x4 acc[4];
  {
    float4 fc = *(const float4*)(g_FC + r*16 + gi*4);
    f32x4 base = (f32x4){fc.x, fc.y, fc.z, fc.w};
    #pragma unroll
    for (int k=0;k<3;++k) {
      float mk = s_mean[k];
      float4 sk = *(const float4*)(g_S + (r*3+k)*16 + gi*4);
      base.x -= mk*sk.x; base.y -= mk*sk.y; base.z -= mk*sk.z; base.w -= mk*sk.w;
    }
    #pragma unroll
    for (int nt=0;nt<4;++nt) acc[nt] = base;
  }

  // ---- 25-tap MFMA loop: swizzled conflict-free B reads ----------------------
  const char* sb = s_raw;
  #pragma unroll 5
  for (int t=0;t<25;++t) {
    const int dy = t/5, dx = t%5;
    const uint4 aw = g_Wm[t*64 + l];
    const s16x8 af = __builtin_bit_cast(s16x8, aw);
    const int lc0  = dx + m;
    const int slot = (gi + lc0 + (lc0 >> 2)) & 3;   // nt-invariant key
    const int base = (((w+dy)*TW) + lc0)*CSTR + slot*16;
    #pragma unroll
    for (int nt=0;nt<4;++nt) {
      const s16x8 bf = __builtin_bit_cast(s16x8,
          *(const uint4*)(sb + base + nt*(16*CSTR)));
      acc[nt] = __builtin_amdgcn_mfma_f32_16x16x32_bf16(af, bf, acc[nt], 0, 0, 0);
    }
  }

  // center values (bf16) for thermo + Coriolis (chunks 0,1 at swizzled slots)
  float Tc[3], ucv[3], vcv[3];
  {
    const int lcc = l + 2;
    const int keyc = (lcc + (lcc >> 2)) & 3;
    const char* cc = sb + (((w+2)*TW) + lcc)*CSTR;
    const uint4 c0v = *(const uint4*)(cc + ((0+keyc)&3)*16);  // s0-7
    const uint2 c1v = *(const uint2*)(cc + ((1+keyc)&3)*16);  // s8-11
    Tc[0]=bflo(c0v.x); ucv[0]=bflo(c0v.y); vcv[0]=bfhi(c0v.y);
    Tc[1]=bflo(c0v.z); ucv[1]=bflo(c0v.w); vcv[1]=bfhi(c0v.w);
    Tc[2]=bflo(c1v.x); ucv[2]=bflo(c1v.y); vcv[2]=bfhi(c1v.y);
  }
  __syncthreads();                              // tile dead; reuse for transpose

  // transpose D fragments -> per-lane all 16 outputs (per-wave region)
  float* sf = (float*)s_raw;
  const int trb = w * (64*TRL);
  #pragma unroll
  for (int nt=0;nt<4;++nt)
    *(f32x4*)(sf + trb + (nt*16 + m)*TRL + gi*4) = acc[nt];
  float y[16];
  #pragma unroll
  for (int q=0;q<4;++q) {
    float4 v = *(const float4*)(sf + trb + l*TRL + q*4);
    y[4*q+0]=v.x; y[4*q+1]=v.y; y[4*q+2]=v.z; y[4*q+3]=v.w;
  }

  // ----------------- physics + RK4 ------------------------------------------
  const int c = c0 + l;
  const float fcv = f_cor[r];
  const float dtf = (float)(*dtp);
  const float an  = (stage==2) ? dtf : 0.5f*dtf;
  const float c6  = dtf/6.0f;
  const float p0=p_lev[0], p1=p_lev[1], p2=p_lev[2];
  const float dp0=delta_p[0], dp1=delta_p[1], dp2=delta_p[2];
  const float r10 = 1.0f/(p1-p0), r20 = 1.0f/(p2-p0), r21 = 1.0f/(p2-p1);
  const float roc = RGASC/CPC;
  const float rp0 = 1.0f/p0, rp1 = 1.0f/p1, rp2 = 1.0f/p2;
  const int OUT_T = BQ*3*HWQ*2;
  const int OUT_Q = OUT_T + BQ*3*HWQ;

  float kT[3], kq[3], ku[3], kv[3];
  #pragma unroll
  for (int k=0;k<3;++k) {
    kT[k] = y[3+k];
    kq[k] = y[6+k];
    ku[k] = y[9+2*k]  + fcv*vcv[k];             // Coriolis (svp collapses to this)
    kv[k] = y[10+2*k] - fcv*ucv[k];
  }
  const float oh1 = y[0]*dp0;
  const float oh2 = oh1 + y[1]*dp1;
  const float oh3 = oh2 + y[2]*dp2;
  const float om0 = 0.5f*oh1, om1 = 0.5f*(oh1+oh2), om2 = 0.5f*(oh2+oh3);
  kT[0] += om0*(roc*Tc[0]*rp0 - (Tc[1]-Tc[0])*r10);
  kT[1] += om1*(roc*Tc[1]*rp1 - (Tc[2]-Tc[0])*r20);
  kT[2] += om2*(roc*Tc[2]*rp2 - (Tc[2]-Tc[1])*r21);

  if (stage < 3) {
    float Tn[3], qn[3], un[3], vn[3];
    #pragma unroll
    for (int k=0;k<3;++k) {
      const int pT = ((b*3+k)*HH + r)*WW + c;
      const int pU = pT*2;
      if (stage == 0) {
        g_aT[pT] = kT[k];  g_aq[pT] = kq[k];
        g_auv[pU] = ku[k]; g_auv[pU+1] = kv[k];
      } else {
        g_aT[pT] += 2.0f*kT[k];  g_aq[pT] += 2.0f*kq[k];
        g_auv[pU] += 2.0f*ku[k]; g_auv[pU+1] += 2.0f*kv[k];
      }
      Tn[k] = T0[pT] + an*kT[k];
      qn[k] = q0[pT] + an*kq[k];
      un[k] = uv0[pU]   + an*ku[k];
      vn[k] = uv0[pU+1] + an*kv[k];
    }
    // packed bf16 state -> parity buffer (stage s writes buf s&1)
    const int sidx = (b*HH + r)*WW + c;
    unsigned int w0 = f2bf(Tn[0]) | ((unsigned)f2bf(qn[0])<<16);
    unsigned int w1 = f2bf(un[0]) | ((unsigned)f2bf(vn[0])<<16);
    unsigned int w2 = f2bf(Tn[1]) | ((unsigned)f2bf(qn[1])<<16);
    unsigned int w3 = f2bf(un[1]) | ((unsigned)f2bf(vn[1])<<16);
    unsigned int w4 = f2bf(Tn[2]) | ((unsigned)f2bf(qn[2])<<16);
    unsigned int w5 = f2bf(un[2]) | ((unsigned)f2bf(vn[2])<<16);
    g_st0[stage & 1][sidx] = make_uint4(w0, w1, w2, w3);
    g_st1[stage & 1][sidx] = make_uint2(w4, w5);

    // partial sums of next-stage T for its mean (opposite parity buffer)
    #pragma unroll
    for (int k=0;k<3;++k) {
      float v = Tn[k];
      #pragma unroll
      for (int off=32; off; off >>= 1) v += __shfl_down(v, off);
      if (l == 0) s_red[w][k] = v;
    }
    __syncthreads();
    if (tid == 0) {
      #pragma unroll
      for (int k=0;k<3;++k) {
        float s = 0.f;
        #pragma unroll
        for (int ww=0;ww<8;++ww) s += s_red[ww][k];
        g_part[(stage & 1) ^ 1][(b*3+k)*512 + blockIdx.y*8 + blockIdx.x] = s;
      }
    }
  } else {
    #pragma unroll
    for (int k=0;k<3;++k) {
      const int pT = ((b*3+k)*HH + r)*WW + c;
      const int pU = pT*2;
      out[pU]         = uv0[pU]   + c6*(g_auv[pU]   + ku[k]);
      out[pU+1]       = uv0[pU+1] + c6*(g_auv[pU+1] + kv[k]);
      out[OUT_T + pT] = T0[pT]    + c6*(g_aT[pT] + kT[k]);
      out[OUT_Q + pT] = q0[pT]    + c6*(g_aq[pT] + kq[k]);
    }
  }
}

// -----------------------------------------------------------------------------
extern "C" void kernel_launch(void* const* d_in, const int* in_sizes, int n_in,
                              void* d_out, int out_size, void* d_ws, size_t ws_size,
                              hipStream_t stream) {
  (void)in_sizes; (void)n_in; (void)d_ws; (void)ws_size; (void)out_size;
  const float* uv0   = (const float*)d_in[0];
  const float* T0    = (const float*)d_in[1];
  const float* q0    = (const float*)d_in[2];
  const float* k_ss  = (const float*)d_in[3];
  const float* k_vs  = (const float*)d_in[4];
  const float* k_sv  = (const float*)d_in[5];
  const float* k_vv  = (const float*)d_in[6];
  const float* k_vs2 = (const float*)d_in[7];
  const float* ke_w  = (const float*)d_in[10];
  const float* f_cor = (const float*)d_in[11];
  const float* p_lev = (const float*)d_in[12];
  const float* dpv   = (const float*)d_in[13];
  const int*   dtp   = (const int*)d_in[14];
  float* out = (float*)d_out;

  // prelude: 768 mean-partial blocks + 71 pack blocks
  prelude_kernel<<<839, 256, 0, stream>>>(T0, k_ss, k_vs, k_sv, k_vv, k_vs2, f_cor);

  for (int st = 0; st < 4; ++st) {
    conv_kernel<<<dim3(8,32,2), 512, 0, stream>>>(
        ke_w, f_cor, p_lev, dpv, uv0, T0, q0, out, dtp, st);
  }
}